// Round 2
// baseline (751.733 us; speedup 1.0000x reference)
//
#include <hip/hip_runtime.h>
#include <hip/hip_bf16.h>

typedef __bf16 bf16x8 __attribute__((ext_vector_type(8)));
typedef float f32x4 __attribute__((ext_vector_type(4)));
typedef unsigned short u16;
typedef u16 u16x8 __attribute__((ext_vector_type(8)));

#define DIM 2048
#define MEM 64
#define KC 2112   /* 2048 + 64 concatenated K */
#define MTOK 32768

__device__ __forceinline__ u16 f2bf(float f) {
  union { float f; unsigned u; } v; v.f = f;
  unsigned r = v.u + 0x7FFF + ((v.u >> 16) & 1);  // RNE
  return (u16)(r >> 16);
}

#define GLDS16(g, l) __builtin_amdgcn_global_load_lds( \
    (const __attribute__((address_space(1))) void*)(g), \
    (__attribute__((address_space(3))) void*)(l), 16, 0, 0)

// ---------------- P1: WcatT[n][k] = bf16(Wu[k][n]) for k < 2048 ----------------
__global__ __launch_bounds__(256) void prep_wu1(const float* __restrict__ Wu,
                                                u16* __restrict__ WcatT) {
  __shared__ float tile[64][65];
  int bk = blockIdx.x & 31;   // k-tile (2048/64)
  int bn = blockIdx.x >> 5;   // n-tile (2048/64)
  int tx = threadIdx.x & 63, g = threadIdx.x >> 6;
#pragma unroll
  for (int i = 0; i < 16; ++i)
    tile[g + i*4][tx] = Wu[(size_t)(bk*64 + g + i*4)*DIM + bn*64 + tx];
  __syncthreads();
#pragma unroll
  for (int i = 0; i < 16; ++i) {
    int n = bn*64 + g + i*4;
    WcatT[(size_t)n*KC + bk*64 + tx] = f2bf(tile[tx][g + i*4]);
  }
}

// ------- P2: WcatT[n][2048+m] = bf16( sum_d ms[m][d] * Wu[2048+d][n] ) -------
__global__ __launch_bounds__(256) void prep_m2(const float* __restrict__ ms,
                                               const float* __restrict__ Wu,
                                               u16* __restrict__ WcatT) {
  int n = blockIdx.x*256 + threadIdx.x;
  int mg = blockIdx.y;        // 16 groups of 4 m's
  const float* w2 = Wu + (size_t)DIM*DIM + n;
  const float* m0 = ms + (size_t)(mg*4+0)*DIM;
  const float* m1 = ms + (size_t)(mg*4+1)*DIM;
  const float* m2 = ms + (size_t)(mg*4+2)*DIM;
  const float* m3 = ms + (size_t)(mg*4+3)*DIM;
  float a0=0.f, a1=0.f, a2=0.f, a3=0.f;
  for (int d = 0; d < DIM; ++d) {
    float w = w2[(size_t)d*DIM];
    a0 += m0[d]*w; a1 += m1[d]*w; a2 += m2[d]*w; a3 += m3[d]*w;
  }
  WcatT[(size_t)n*KC + DIM + mg*4 + 0] = f2bf(a0);
  WcatT[(size_t)n*KC + DIM + mg*4 + 1] = f2bf(a1);
  WcatT[(size_t)n*KC + DIM + mg*4 + 2] = f2bf(a2);
  WcatT[(size_t)n*KC + DIM + mg*4 + 3] = f2bf(a3);
}

// ---------------- P3: WgT[m][k] = bf16(Wg[k][m]) ----------------
__global__ __launch_bounds__(256) void prep_wg(const float* __restrict__ Wg,
                                               u16* __restrict__ WgT) {
  __shared__ float tile[64][65];
  int k0 = blockIdx.x * 64;
  int tx = threadIdx.x & 63, g = threadIdx.x >> 6;
#pragma unroll
  for (int i = 0; i < 16; ++i)
    tile[g + i*4][tx] = Wg[(size_t)(k0 + g + i*4)*MEM + tx];
  __syncthreads();
#pragma unroll
  for (int i = 0; i < 16; ++i) {
    int m = g + i*4;
    WgT[(size_t)m*DIM + k0 + tx] = f2bf(tile[tx][m]);
  }
}

// ---------------- A1: Acat[t][0:2048] = bf16(x[t][:]) ----------------
__global__ __launch_bounds__(256) void conv_x(const float* __restrict__ x,
                                              u16* __restrict__ Acat) {
  size_t i = ((size_t)blockIdx.x*256 + threadIdx.x) * 8;
  size_t t = i >> 11;
  int c = (int)(i & 2047);
  const float4* p = reinterpret_cast<const float4*>(x + i);
  float4 a = p[0], b = p[1];
  u16x8 o;
  o[0]=f2bf(a.x); o[1]=f2bf(a.y); o[2]=f2bf(a.z); o[3]=f2bf(a.w);
  o[4]=f2bf(b.x); o[5]=f2bf(b.y); o[6]=f2bf(b.z); o[7]=f2bf(b.w);
  *reinterpret_cast<u16x8*>(Acat + t*KC + c) = o;
}

// ------- A2: Acat[t][2048+c] = bf16(sigmoid(X@Wg + bg)), MFMA mini-GEMM -------
__global__ __launch_bounds__(256) void gates_gemm(const u16* __restrict__ Acat,
                                                  const u16* __restrict__ WgT,
                                                  const float* __restrict__ bg,
                                                  u16* __restrict__ Aout) {
  __shared__ u16 As[128*32];
  __shared__ u16 Bs[64*32];
  int brow = blockIdx.x;
  int tid = threadIdx.x;
  int w = tid >> 6, l = tid & 63;
  int lrow = l & 15, lk = l >> 4;

  const u16* Ag  = Acat + (size_t)(brow*128 + (tid>>2))*KC + (tid&3)*8;
  const u16* Ag2 = Acat + (size_t)(brow*128 + 64 + (tid>>2))*KC + (tid&3)*8;
  const u16* Bg  = WgT  + (size_t)(tid>>2)*DIM + (tid&3)*8;
  u16* Asd  = As + tid*8;
  u16* Asd2 = As + 2048 + tid*8;
  u16* Bsd  = Bs + tid*8;

  f32x4 acc[2][4] = {};
  const bf16x8* Al = reinterpret_cast<const bf16x8*>(As);
  const bf16x8* Bl = reinterpret_cast<const bf16x8*>(Bs);
  int abase = (w*32 + lrow)*4 + lk;
  int bbase = lrow*4 + lk;

  for (int k0 = 0; k0 < DIM; k0 += 32) {
    GLDS16(Ag, Asd); GLDS16(Ag2, Asd2); GLDS16(Bg, Bsd);
    Ag += 32; Ag2 += 32; Bg += 32;
    __syncthreads();
    bf16x8 av[2], bv[4];
#pragma unroll
    for (int m = 0; m < 2; ++m) av[m] = Al[abase + m*64];
#pragma unroll
    for (int n = 0; n < 4; ++n) bv[n] = Bl[bbase + n*64];
#pragma unroll
    for (int m = 0; m < 2; ++m)
#pragma unroll
      for (int n = 0; n < 4; ++n)
        acc[m][n] = __builtin_amdgcn_mfma_f32_16x16x32_bf16(av[m], bv[n], acc[m][n], 0, 0, 0);
    __syncthreads();
  }

#pragma unroll
  for (int n = 0; n < 4; ++n) {
    int c = n*16 + lrow;
    float b = bg[c];
#pragma unroll
    for (int m = 0; m < 2; ++m)
#pragma unroll
      for (int r = 0; r < 4; ++r) {
        int t = brow*128 + w*32 + m*16 + lk*4 + r;
        float logit = acc[m][n][r] + b;
        float gv = 1.0f / (1.0f + __expf(-logit));
        Aout[(size_t)t*KC + DIM + c] = f2bf(gv);
      }
  }
}

// ------------- Main GEMM: H = Acat[32768x2112] @ WcatT^T + bu (fp32 out) -------------
__global__ __launch_bounds__(256) void gemm_main(const u16* __restrict__ A,
                                                 const u16* __restrict__ Bt,
                                                 const float* __restrict__ bu,
                                                 float* __restrict__ H) {
  __shared__ u16 As[128*32];
  __shared__ u16 Bs[128*32];
  int bid = blockIdx.x;
  int cpx = gridDim.x >> 3;                 // 4096 % 8 == 0
  int wg = (bid & 7) * cpx + (bid >> 3);    // XCD-aware swizzle
  int brow = wg >> 4;                        // N/BN = 16
  int bcol = wg & 15;
  int tid = threadIdx.x;
  int w = tid >> 6, l = tid & 63;
  int wr = w >> 1, wc = w & 1;
  int lrow = l & 15, lk = l >> 4;

  // Full 128-row staging: two 16B loads per operand per k-step (BUGFIX vs r0:
  // previously only rows 0..63 were staged; rows 64..127 read uninit LDS -> NaN).
  const u16* Ag  = A  + (size_t)(brow*128 + (tid>>2))*KC + (tid&3)*8;
  const u16* Ag2 = Ag + (size_t)64*KC;
  const u16* Bg  = Bt + (size_t)(bcol*128 + (tid>>2))*KC + (tid&3)*8;
  const u16* Bg2 = Bg + (size_t)64*KC;
  u16* Asd  = As + tid*8;
  u16* Asd2 = As + 2048 + tid*8;
  u16* Bsd  = Bs + tid*8;
  u16* Bsd2 = Bs + 2048 + tid*8;

  f32x4 acc[4][4] = {};
  const bf16x8* Al = reinterpret_cast<const bf16x8*>(As);
  const bf16x8* Bl = reinterpret_cast<const bf16x8*>(Bs);
  int abase = (wr*64 + lrow)*4 + lk;
  int bbase = (wc*64 + lrow)*4 + lk;

  for (int k0 = 0; k0 < KC; k0 += 32) {
    GLDS16(Ag,  Asd);
    GLDS16(Ag2, Asd2);
    GLDS16(Bg,  Bsd);
    GLDS16(Bg2, Bsd2);
    Ag += 32; Ag2 += 32; Bg += 32; Bg2 += 32;
    __syncthreads();
    bf16x8 av[4], bv[4];
#pragma unroll
    for (int m = 0; m < 4; ++m) av[m] = Al[abase + m*64];
#pragma unroll
    for (int n = 0; n < 4; ++n) bv[n] = Bl[bbase + n*64];
#pragma unroll
    for (int m = 0; m < 4; ++m)
#pragma unroll
      for (int n = 0; n < 4; ++n)
        acc[m][n] = __builtin_amdgcn_mfma_f32_16x16x32_bf16(av[m], bv[n], acc[m][n], 0, 0, 0);
    __syncthreads();
  }

  int row0 = brow*128 + wr*64;
  int col0 = bcol*128 + wc*64;
#pragma unroll
  for (int n = 0; n < 4; ++n) {
    int c = col0 + n*16 + lrow;
    float bias = bu[c];
#pragma unroll
    for (int m = 0; m < 4; ++m)
#pragma unroll
      for (int r = 0; r < 4; ++r) {
        int t = row0 + m*16 + lk*4 + r;
        H[(size_t)t*DIM + c] = acc[m][n][r] + bias;
      }
  }
}

// ---------------- LN (in-place on d_out) ----------------
__global__ __launch_bounds__(256) void ln_inplace(float* __restrict__ H,
                                                  const float* __restrict__ gamma,
                                                  const float* __restrict__ beta) {
  int row = blockIdx.x;
  float* h = H + (size_t)row*DIM;
  int tid = threadIdx.x;
  float4 a = reinterpret_cast<const float4*>(h)[tid*2];
  float4 b = reinterpret_cast<const float4*>(h)[tid*2+1];
  float v[8] = {a.x,a.y,a.z,a.w,b.x,b.y,b.z,b.w};
  float s = 0.f, s2 = 0.f;
#pragma unroll
  for (int j = 0; j < 8; ++j) { s += v[j]; s2 += v[j]*v[j]; }
#pragma unroll
  for (int o = 32; o >= 1; o >>= 1) { s += __shfl_xor(s, o); s2 += __shfl_xor(s2, o); }
  __shared__ float ss[4], ss2[4];
  int w = tid >> 6;
  if ((tid & 63) == 0) { ss[w] = s; ss2[w] = s2; }
  __syncthreads();
  s  = ss[0]+ss[1]+ss[2]+ss[3];
  s2 = ss2[0]+ss2[1]+ss2[2]+ss2[3];
  float mu  = s * (1.0f/DIM);
  float var = s2 * (1.0f/DIM) - mu*mu;
  float rs  = rsqrtf(var + 1e-5f);
  int c0 = tid*8;
  float o8[8];
#pragma unroll
  for (int j = 0; j < 8; ++j) o8[j] = (v[j]-mu)*rs*gamma[c0+j] + beta[c0+j];
  float4 oa = {o8[0],o8[1],o8[2],o8[3]}, ob = {o8[4],o8[5],o8[6],o8[7]};
  reinterpret_cast<float4*>(h)[tid*2]   = oa;
  reinterpret_cast<float4*>(h)[tid*2+1] = ob;
}

extern "C" void kernel_launch(void* const* d_in, const int* in_sizes, int n_in,
                              void* d_out, int out_size, void* d_ws, size_t ws_size,
                              hipStream_t stream) {
  const float* x     = (const float*)d_in[0];
  const float* ms    = (const float*)d_in[1];
  const float* Wg    = (const float*)d_in[2];
  const float* bg    = (const float*)d_in[3];
  const float* Wu    = (const float*)d_in[4];
  const float* bu    = (const float*)d_in[5];
  const float* gamma = (const float*)d_in[6];
  const float* beta  = (const float*)d_in[7];
  float* out = (float*)d_out;

  char* wsp = (char*)d_ws;
  u16* Acat  = (u16*)wsp;                                                 // 32768*2112*2 = 138,412,032 B
  u16* WcatT = (u16*)(wsp + (size_t)MTOK*KC*2);                           // 2048*2112*2 = 8,650,752 B
  u16* WgT   = (u16*)(wsp + (size_t)MTOK*KC*2 + (size_t)DIM*KC*2);        // 64*2048*2 = 262,144 B

  prep_wu1<<<1024, 256, 0, stream>>>(Wu, WcatT);
  prep_m2<<<dim3(8,16), 256, 0, stream>>>(ms, Wu, WcatT);
  prep_wg<<<32, 256, 0, stream>>>(Wg, WgT);
  conv_x<<<32768, 256, 0, stream>>>(x, Acat);
  gates_gemm<<<256, 256, 0, stream>>>(Acat, WgT, bg, Acat);
  gemm_main<<<4096, 256, 0, stream>>>(Acat, WcatT, bu, out);
  ln_inplace<<<32768, 256, 0, stream>>>(out, gamma, beta);
}

// Round 3
// 649.721 us; speedup vs baseline: 1.1570x; 1.1570x over previous
//
#include <hip/hip_runtime.h>
#include <hip/hip_bf16.h>

typedef __bf16 bf16x8 __attribute__((ext_vector_type(8)));
typedef float f32x4 __attribute__((ext_vector_type(4)));
typedef unsigned short u16;
typedef u16 u16x8 __attribute__((ext_vector_type(8)));

#define DIM 2048
#define MEM 64
#define KC 2112   /* 2048 + 64 concatenated K */
#define MTOK 32768
#define BK 32
#define NT (KC/BK)   /* 66 K-tiles */

__device__ __forceinline__ u16 f2bf(float f) {
  union { float f; unsigned u; } v; v.f = f;
  unsigned r = v.u + 0x7FFF + ((v.u >> 16) & 1);  // RNE
  return (u16)(r >> 16);
}

#define GLDS16(g, l) __builtin_amdgcn_global_load_lds( \
    (const __attribute__((address_space(1))) void*)(g), \
    (__attribute__((address_space(3))) void*)(l), 16, 0, 0)

// ---------------- P1: WcatT[n][k] = bf16(Wu[k][n]) for k < 2048 ----------------
__global__ __launch_bounds__(256) void prep_wu1(const float* __restrict__ Wu,
                                                u16* __restrict__ WcatT) {
  __shared__ float tile[64][65];
  int bk = blockIdx.x & 31;   // k-tile (2048/64)
  int bn = blockIdx.x >> 5;   // n-tile (2048/64)
  int tx = threadIdx.x & 63, g = threadIdx.x >> 6;
#pragma unroll
  for (int i = 0; i < 16; ++i)
    tile[g + i*4][tx] = Wu[(size_t)(bk*64 + g + i*4)*DIM + bn*64 + tx];
  __syncthreads();
#pragma unroll
  for (int i = 0; i < 16; ++i) {
    int n = bn*64 + g + i*4;
    WcatT[(size_t)n*KC + bk*64 + tx] = f2bf(tile[tx][g + i*4]);
  }
}

// ------- P2a: split-K partials of M2 = ms @ Wu2 (deterministic, no atomics) -------
__global__ __launch_bounds__(256) void prep_m2a(const float* __restrict__ ms,
                                                const float* __restrict__ Wu,
                                                float* __restrict__ M2p) {
  int n  = blockIdx.x*256 + threadIdx.x;   // 8 blocks
  int mg = blockIdx.y;                     // 16 groups of 4 m
  int kc = blockIdx.z;                     // 8 k-chunks of 256
  const float* w2 = Wu + (size_t)DIM*DIM + n;
  const float* m0 = ms + (size_t)(mg*4+0)*DIM;
  const float* m1 = ms + (size_t)(mg*4+1)*DIM;
  const float* m2 = ms + (size_t)(mg*4+2)*DIM;
  const float* m3 = ms + (size_t)(mg*4+3)*DIM;
  float a0=0.f, a1=0.f, a2=0.f, a3=0.f;
  int d0 = kc*256;
  for (int d = d0; d < d0+256; ++d) {
    float w = w2[(size_t)d*DIM];
    a0 += m0[d]*w; a1 += m1[d]*w; a2 += m2[d]*w; a3 += m3[d]*w;
  }
  M2p[((size_t)kc*64 + mg*4 + 0)*2048 + n] = a0;
  M2p[((size_t)kc*64 + mg*4 + 1)*2048 + n] = a1;
  M2p[((size_t)kc*64 + mg*4 + 2)*2048 + n] = a2;
  M2p[((size_t)kc*64 + mg*4 + 3)*2048 + n] = a3;
}

// ------- P2b: reduce partials -> WcatT[n][2048+m] -------
__global__ __launch_bounds__(256) void prep_m2b(const float* __restrict__ M2p,
                                                u16* __restrict__ WcatT) {
  int i = blockIdx.x*256 + threadIdx.x;    // 512 blocks, i = m*2048 + n
  float s = 0.f;
#pragma unroll
  for (int kc = 0; kc < 8; ++kc) s += M2p[(size_t)kc*131072 + i];
  int m = i >> 11, n = i & 2047;
  WcatT[(size_t)n*KC + DIM + m] = f2bf(s);
}

// ---------------- P3: WgT[m][k] = bf16(Wg[k][m]) ----------------
__global__ __launch_bounds__(256) void prep_wg(const float* __restrict__ Wg,
                                               u16* __restrict__ WgT) {
  __shared__ float tile[64][65];
  int k0 = blockIdx.x * 64;
  int tx = threadIdx.x & 63, g = threadIdx.x >> 6;
#pragma unroll
  for (int i = 0; i < 16; ++i)
    tile[g + i*4][tx] = Wg[(size_t)(k0 + g + i*4)*MEM + tx];
  __syncthreads();
#pragma unroll
  for (int i = 0; i < 16; ++i) {
    int m = g + i*4;
    WgT[(size_t)m*DIM + k0 + tx] = f2bf(tile[tx][m]);
  }
}

// ---------------- A1: Acat[t][0:2048] = bf16(x[t][:]) ----------------
__global__ __launch_bounds__(256) void conv_x(const float* __restrict__ x,
                                              u16* __restrict__ Acat) {
  size_t i = ((size_t)blockIdx.x*256 + threadIdx.x) * 8;
  size_t t = i >> 11;
  int c = (int)(i & 2047);
  const float4* p = reinterpret_cast<const float4*>(x + i);
  float4 a = p[0], b = p[1];
  u16x8 o;
  o[0]=f2bf(a.x); o[1]=f2bf(a.y); o[2]=f2bf(a.z); o[3]=f2bf(a.w);
  o[4]=f2bf(b.x); o[5]=f2bf(b.y); o[6]=f2bf(b.z); o[7]=f2bf(b.w);
  *reinterpret_cast<u16x8*>(Acat + t*KC + c) = o;
}

// ------- A2: Acat[t][2048+c] = bf16(sigmoid(X@Wg + bg)), MFMA mini-GEMM -------
__global__ __launch_bounds__(256) void gates_gemm(const u16* __restrict__ Acat,
                                                  const u16* __restrict__ WgT,
                                                  const float* __restrict__ bg,
                                                  u16* __restrict__ Aout) {
  __shared__ u16 As[128*32];
  __shared__ u16 Bs[64*32];
  int brow = blockIdx.x;
  int tid = threadIdx.x;
  int w = tid >> 6, l = tid & 63;
  int lrow = l & 15, lk = l >> 4;

  const u16* Ag  = Acat + (size_t)(brow*128 + (tid>>2))*KC + (tid&3)*8;
  const u16* Ag2 = Acat + (size_t)(brow*128 + 64 + (tid>>2))*KC + (tid&3)*8;
  const u16* Bg  = WgT  + (size_t)(tid>>2)*DIM + (tid&3)*8;
  u16* Asd  = As + tid*8;
  u16* Asd2 = As + 2048 + tid*8;
  u16* Bsd  = Bs + tid*8;

  f32x4 acc[2][4] = {};
  const bf16x8* Al = reinterpret_cast<const bf16x8*>(As);
  const bf16x8* Bl = reinterpret_cast<const bf16x8*>(Bs);
  int abase = (w*32 + lrow)*4 + lk;
  int bbase = lrow*4 + lk;

  for (int k0 = 0; k0 < DIM; k0 += 32) {
    GLDS16(Ag, Asd); GLDS16(Ag2, Asd2); GLDS16(Bg, Bsd);
    Ag += 32; Ag2 += 32; Bg += 32;
    __syncthreads();
    bf16x8 av[2], bv[4];
#pragma unroll
    for (int m = 0; m < 2; ++m) av[m] = Al[abase + m*64];
#pragma unroll
    for (int n = 0; n < 4; ++n) bv[n] = Bl[bbase + n*64];
#pragma unroll
    for (int m = 0; m < 2; ++m)
#pragma unroll
      for (int n = 0; n < 4; ++n)
        acc[m][n] = __builtin_amdgcn_mfma_f32_16x16x32_bf16(av[m], bv[n], acc[m][n], 0, 0, 0);
    __syncthreads();
  }

#pragma unroll
  for (int n = 0; n < 4; ++n) {
    int c = n*16 + lrow;
    float b = bg[c];
#pragma unroll
    for (int m = 0; m < 2; ++m)
#pragma unroll
      for (int r = 0; r < 4; ++r) {
        int t = brow*128 + w*32 + m*16 + lk*4 + r;
        float logit = acc[m][n][r] + b;
        float gv = 1.0f / (1.0f + __expf(-logit));
        Aout[(size_t)t*KC + DIM + c] = f2bf(gv);
      }
  }
}

// ------------- Main GEMM: 256x256 tile, 8 waves (2x4), BK=32, 4-buf depth-3
// pipeline, counted vmcnt, LDS XOR swizzle, setprio. H = Acat @ WcatT^T + bu -------------
__global__ __launch_bounds__(512, 2) void gemm_main8(const u16* __restrict__ A,
                                                     const u16* __restrict__ Bt,
                                                     const float* __restrict__ bu,
                                                     float* __restrict__ H) {
  __shared__ u16 AsB[4*8192];   // 4 bufs x 16 KiB
  __shared__ u16 BsB[4*8192];

  const int bid = blockIdx.x;
  const int wg  = (bid & 7) * (int)(gridDim.x >> 3) + (bid >> 3);  // XCD swizzle (1024%8==0)
  const int brow = wg >> 3;    // M/256 = 128 row tiles
  const int bcol = wg & 7;     // N/256 = 8 col tiles
  const int tid = threadIdx.x;
  const int w = tid >> 6, l = tid & 63;
  const int wm = w >> 2, wn = w & 3;       // 2 x 4 wave grid
  const int lrow = l & 15, lk = l >> 4;

  // Staging: linear LDS dest p; logical addr lp = p ^ swz(p-row-bits).
  // Swizzle (64B rows): byte ^= ((row&2)<<4) ^ ((row&4)<<2)  [row bits at byte 7,8]
  const int p0 = tid * 16, p1 = 8192 + tid * 16;
  const int lp0 = p0 ^ (((p0 >> 7) & 1) << 5) ^ (((p0 >> 8) & 1) << 4);
  const int lp1 = p1 ^ (((p1 >> 7) & 1) << 5) ^ (((p1 >> 8) & 1) << 4);
  const int r0 = lp0 >> 6, c0 = (lp0 & 63) >> 1;
  const int r1 = lp1 >> 6, c1 = (lp1 & 63) >> 1;

  const u16* Asrc0 = A  + (size_t)(brow*256 + r0)*KC + c0;
  const u16* Asrc1 = A  + (size_t)(brow*256 + r1)*KC + c1;
  const u16* Bsrc0 = Bt + (size_t)(bcol*256 + r0)*KC + c0;
  const u16* Bsrc1 = Bt + (size_t)(bcol*256 + r1)*KC + c1;
  char* AsC = (char*)AsB;
  char* BsC = (char*)BsB;

  // Read-side physical byte offsets (same involution)
  const int asw = ((lrow & 2) << 4) | ((lrow & 4) << 2);
  int aoff[8], boff[4];
#pragma unroll
  for (int rf = 0; rf < 8; ++rf)
    aoff[rf] = (((wm*128 + rf*16 + lrow)*64) + lk*16) ^ asw;
#pragma unroll
  for (int cf = 0; cf < 4; ++cf)
    boff[cf] = (((wn*64 + cf*16 + lrow)*64) + lk*16) ^ asw;

  f32x4 acc[8][4] = {};

#define STAGE_T(kt) { const int bb_ = ((kt)&3)*16384; \
    GLDS16(Asrc0 + (size_t)(kt)*BK, AsC + bb_ + p0); \
    GLDS16(Asrc1 + (size_t)(kt)*BK, AsC + bb_ + p1); \
    GLDS16(Bsrc0 + (size_t)(kt)*BK, BsC + bb_ + p0); \
    GLDS16(Bsrc1 + (size_t)(kt)*BK, BsC + bb_ + p1); }

  STAGE_T(0); STAGE_T(1); STAGE_T(2);

#pragma unroll 1
  for (int t = 0; t < NT; ++t) {
    if (t + 3 < NT) STAGE_T(t + 3);
    if (t < NT-3)        { asm volatile("s_waitcnt vmcnt(12)" ::: "memory"); }
    else if (t == NT-3)  { asm volatile("s_waitcnt vmcnt(8)"  ::: "memory"); }
    else if (t == NT-2)  { asm volatile("s_waitcnt vmcnt(4)"  ::: "memory"); }
    else                 { asm volatile("s_waitcnt vmcnt(0)"  ::: "memory"); }
    __builtin_amdgcn_sched_barrier(0);
    __builtin_amdgcn_s_barrier();
    __builtin_amdgcn_sched_barrier(0);

    const char* Ab = AsC + (t & 3) * 16384;
    const char* Bb = BsC + (t & 3) * 16384;
    bf16x8 av[8], bv[4];
#pragma unroll
    for (int rf = 0; rf < 8; ++rf) av[rf] = *(const bf16x8*)(Ab + aoff[rf]);
#pragma unroll
    for (int cf = 0; cf < 4; ++cf) bv[cf] = *(const bf16x8*)(Bb + boff[cf]);
    __builtin_amdgcn_s_setprio(1);
#pragma unroll
    for (int rf = 0; rf < 8; ++rf)
#pragma unroll
      for (int cf = 0; cf < 4; ++cf)
        acc[rf][cf] = __builtin_amdgcn_mfma_f32_16x16x32_bf16(av[rf], bv[cf], acc[rf][cf], 0, 0, 0);
    __builtin_amdgcn_s_setprio(0);
    asm volatile("s_waitcnt lgkmcnt(0)" ::: "memory");
    __builtin_amdgcn_sched_barrier(0);
    __builtin_amdgcn_s_barrier();
    __builtin_amdgcn_sched_barrier(0);
  }
#undef STAGE_T

  const int orow = brow*256 + wm*128 + lk*4;
  const int ocol = bcol*256 + wn*64 + lrow;
#pragma unroll
  for (int cf = 0; cf < 4; ++cf) {
    const int c = ocol + cf*16;
    const float bias = bu[c];
#pragma unroll
    for (int rf = 0; rf < 8; ++rf) {
      const int rr = orow + rf*16;
#pragma unroll
      for (int r = 0; r < 4; ++r)
        H[(size_t)(rr + r)*DIM + c] = acc[rf][cf][r] + bias;
    }
  }
}

// ---------------- LN (in-place on d_out) ----------------
__global__ __launch_bounds__(256) void ln_inplace(float* __restrict__ H,
                                                  const float* __restrict__ gamma,
                                                  const float* __restrict__ beta) {
  int row = blockIdx.x;
  float* h = H + (size_t)row*DIM;
  int tid = threadIdx.x;
  float4 a = reinterpret_cast<const float4*>(h)[tid*2];
  float4 b = reinterpret_cast<const float4*>(h)[tid*2+1];
  float v[8] = {a.x,a.y,a.z,a.w,b.x,b.y,b.z,b.w};
  float s = 0.f, s2 = 0.f;
#pragma unroll
  for (int j = 0; j < 8; ++j) { s += v[j]; s2 += v[j]*v[j]; }
#pragma unroll
  for (int o = 32; o >= 1; o >>= 1) { s += __shfl_xor(s, o); s2 += __shfl_xor(s2, o); }
  __shared__ float ss[4], ss2[4];
  int w = tid >> 6;
  if ((tid & 63) == 0) { ss[w] = s; ss2[w] = s2; }
  __syncthreads();
  s  = ss[0]+ss[1]+ss[2]+ss[3];
  s2 = ss2[0]+ss2[1]+ss2[2]+ss2[3];
  float mu  = s * (1.0f/DIM);
  float var = s2 * (1.0f/DIM) - mu*mu;
  float rs  = rsqrtf(var + 1e-5f);
  int c0 = tid*8;
  float o8[8];
#pragma unroll
  for (int j = 0; j < 8; ++j) o8[j] = (v[j]-mu)*rs*gamma[c0+j] + beta[c0+j];
  float4 oa = {o8[0],o8[1],o8[2],o8[3]}, ob = {o8[4],o8[5],o8[6],o8[7]};
  reinterpret_cast<float4*>(h)[tid*2]   = oa;
  reinterpret_cast<float4*>(h)[tid*2+1] = ob;
}

extern "C" void kernel_launch(void* const* d_in, const int* in_sizes, int n_in,
                              void* d_out, int out_size, void* d_ws, size_t ws_size,
                              hipStream_t stream) {
  const float* x     = (const float*)d_in[0];
  const float* ms    = (const float*)d_in[1];
  const float* Wg    = (const float*)d_in[2];
  const float* bg    = (const float*)d_in[3];
  const float* Wu    = (const float*)d_in[4];
  const float* bu    = (const float*)d_in[5];
  const float* gamma = (const float*)d_in[6];
  const float* beta  = (const float*)d_in[7];
  float* out = (float*)d_out;

  char* wsp = (char*)d_ws;
  u16* Acat  = (u16*)wsp;                                                 // 138,412,032 B
  u16* WcatT = (u16*)(wsp + (size_t)MTOK*KC*2);                           // 8,650,752 B
  u16* WgT   = (u16*)(wsp + (size_t)MTOK*KC*2 + (size_t)DIM*KC*2);        // 262,144 B
  float* M2p = (float*)wsp;  // 4 MiB partials, aliases Acat (consumed before conv_x)

  prep_m2a<<<dim3(8,16,8), 256, 0, stream>>>(ms, Wu, M2p);
  prep_m2b<<<512, 256, 0, stream>>>(M2p, WcatT);
  prep_wu1<<<1024, 256, 0, stream>>>(Wu, WcatT);
  prep_wg<<<32, 256, 0, stream>>>(Wg, WgT);
  conv_x<<<32768, 256, 0, stream>>>(x, Acat);
  gates_gemm<<<256, 256, 0, stream>>>(Acat, WgT, bg, Acat);
  gemm_main8<<<1024, 512, 0, stream>>>(Acat, WcatT, bu, out);
  ln_inplace<<<32768, 256, 0, stream>>>(out, gamma, beta);
}

// Round 4
// 582.905 us; speedup vs baseline: 1.2896x; 1.1146x over previous
//
#include <hip/hip_runtime.h>
#include <hip/hip_bf16.h>

typedef __bf16 bf16x8 __attribute__((ext_vector_type(8)));
typedef float f32x4 __attribute__((ext_vector_type(4)));
typedef unsigned short u16;
typedef u16 u16x8 __attribute__((ext_vector_type(8)));

#define DIM 2048
#define MEM 64
#define KC 2112   /* 2048 + 64 concatenated K */
#define MTOK 32768
#define BK 32
#define NT (KC/BK)   /* 66 K-tiles */

__device__ __forceinline__ u16 f2bf(float f) {
  union { float f; unsigned u; } v; v.f = f;
  unsigned r = v.u + 0x7FFF + ((v.u >> 16) & 1);  // RNE
  return (u16)(r >> 16);
}

#define GLDS16(g, l) __builtin_amdgcn_global_load_lds( \
    (const __attribute__((address_space(1))) void*)(g), \
    (__attribute__((address_space(3))) void*)(l), 16, 0, 0)

// ---------------- P1: WcatT[n][k] = bf16(Wu[k][n]) for k < 2048 ----------------
__global__ __launch_bounds__(256) void prep_wu1(const float* __restrict__ Wu,
                                                u16* __restrict__ WcatT) {
  __shared__ float tile[64][65];
  int bk = blockIdx.x & 31;   // k-tile (2048/64)
  int bn = blockIdx.x >> 5;   // n-tile (2048/64)
  int tx = threadIdx.x & 63, g = threadIdx.x >> 6;
#pragma unroll
  for (int i = 0; i < 16; ++i)
    tile[g + i*4][tx] = Wu[(size_t)(bk*64 + g + i*4)*DIM + bn*64 + tx];
  __syncthreads();
#pragma unroll
  for (int i = 0; i < 16; ++i) {
    int n = bn*64 + g + i*4;
    WcatT[(size_t)n*KC + bk*64 + tx] = f2bf(tile[tx][g + i*4]);
  }
}

// ------- P2a: split-K partials of M2 = ms @ Wu2 (deterministic, no atomics) -------
__global__ __launch_bounds__(256) void prep_m2a(const float* __restrict__ ms,
                                                const float* __restrict__ Wu,
                                                float* __restrict__ M2p) {
  int n  = blockIdx.x*256 + threadIdx.x;   // 8 blocks
  int mg = blockIdx.y;                     // 16 groups of 4 m
  int kc = blockIdx.z;                     // 8 k-chunks of 256
  const float* w2 = Wu + (size_t)DIM*DIM + n;
  const float* m0 = ms + (size_t)(mg*4+0)*DIM;
  const float* m1 = ms + (size_t)(mg*4+1)*DIM;
  const float* m2 = ms + (size_t)(mg*4+2)*DIM;
  const float* m3 = ms + (size_t)(mg*4+3)*DIM;
  float a0=0.f, a1=0.f, a2=0.f, a3=0.f;
  int d0 = kc*256;
  for (int d = d0; d < d0+256; ++d) {
    float w = w2[(size_t)d*DIM];
    a0 += m0[d]*w; a1 += m1[d]*w; a2 += m2[d]*w; a3 += m3[d]*w;
  }
  M2p[((size_t)kc*64 + mg*4 + 0)*2048 + n] = a0;
  M2p[((size_t)kc*64 + mg*4 + 1)*2048 + n] = a1;
  M2p[((size_t)kc*64 + mg*4 + 2)*2048 + n] = a2;
  M2p[((size_t)kc*64 + mg*4 + 3)*2048 + n] = a3;
}

// ------- P2b: reduce partials -> WcatT[n][2048+m] -------
__global__ __launch_bounds__(256) void prep_m2b(const float* __restrict__ M2p,
                                                u16* __restrict__ WcatT) {
  int i = blockIdx.x*256 + threadIdx.x;    // 512 blocks, i = m*2048 + n
  float s = 0.f;
#pragma unroll
  for (int kc = 0; kc < 8; ++kc) s += M2p[(size_t)kc*131072 + i];
  int m = i >> 11, n = i & 2047;
  WcatT[(size_t)n*KC + DIM + m] = f2bf(s);
}

// ---------------- P3: WgT[m][k] = bf16(Wg[k][m]) ----------------
__global__ __launch_bounds__(256) void prep_wg(const float* __restrict__ Wg,
                                               u16* __restrict__ WgT) {
  __shared__ float tile[64][65];
  int k0 = blockIdx.x * 64;
  int tx = threadIdx.x & 63, g = threadIdx.x >> 6;
#pragma unroll
  for (int i = 0; i < 16; ++i)
    tile[g + i*4][tx] = Wg[(size_t)(k0 + g + i*4)*MEM + tx];
  __syncthreads();
#pragma unroll
  for (int i = 0; i < 16; ++i) {
    int m = g + i*4;
    WgT[(size_t)m*DIM + k0 + tx] = f2bf(tile[tx][m]);
  }
}

// ---------------- A1: Acat[t][0:2048] = bf16(x[t][:]) ----------------
__global__ __launch_bounds__(256) void conv_x(const float* __restrict__ x,
                                              u16* __restrict__ Acat) {
  size_t i = ((size_t)blockIdx.x*256 + threadIdx.x) * 8;
  size_t t = i >> 11;
  int c = (int)(i & 2047);
  const float4* p = reinterpret_cast<const float4*>(x + i);
  float4 a = p[0], b = p[1];
  u16x8 o;
  o[0]=f2bf(a.x); o[1]=f2bf(a.y); o[2]=f2bf(a.z); o[3]=f2bf(a.w);
  o[4]=f2bf(b.x); o[5]=f2bf(b.y); o[6]=f2bf(b.z); o[7]=f2bf(b.w);
  *reinterpret_cast<u16x8*>(Acat + t*KC + c) = o;
}

// ------- A2: Acat[t][2048+c] = bf16(sigmoid(X@Wg + bg)), MFMA mini-GEMM -------
__global__ __launch_bounds__(256) void gates_gemm(const u16* __restrict__ Acat,
                                                  const u16* __restrict__ WgT,
                                                  const float* __restrict__ bg,
                                                  u16* __restrict__ Aout) {
  __shared__ u16 As[128*32];
  __shared__ u16 Bs[64*32];
  int brow = blockIdx.x;
  int tid = threadIdx.x;
  int w = tid >> 6, l = tid & 63;
  int lrow = l & 15, lk = l >> 4;

  const u16* Ag  = Acat + (size_t)(brow*128 + (tid>>2))*KC + (tid&3)*8;
  const u16* Ag2 = Acat + (size_t)(brow*128 + 64 + (tid>>2))*KC + (tid&3)*8;
  const u16* Bg  = WgT  + (size_t)(tid>>2)*DIM + (tid&3)*8;
  u16* Asd  = As + tid*8;
  u16* Asd2 = As + 2048 + tid*8;
  u16* Bsd  = Bs + tid*8;

  f32x4 acc[2][4] = {};
  const bf16x8* Al = reinterpret_cast<const bf16x8*>(As);
  const bf16x8* Bl = reinterpret_cast<const bf16x8*>(Bs);
  int abase = (w*32 + lrow)*4 + lk;
  int bbase = lrow*4 + lk;

  for (int k0 = 0; k0 < DIM; k0 += 32) {
    GLDS16(Ag, Asd); GLDS16(Ag2, Asd2); GLDS16(Bg, Bsd);
    Ag += 32; Ag2 += 32; Bg += 32;
    __syncthreads();
    bf16x8 av[2], bv[4];
#pragma unroll
    for (int m = 0; m < 2; ++m) av[m] = Al[abase + m*64];
#pragma unroll
    for (int n = 0; n < 4; ++n) bv[n] = Bl[bbase + n*64];
#pragma unroll
    for (int m = 0; m < 2; ++m)
#pragma unroll
      for (int n = 0; n < 4; ++n)
        acc[m][n] = __builtin_amdgcn_mfma_f32_16x16x32_bf16(av[m], bv[n], acc[m][n], 0, 0, 0);
    __syncthreads();
  }

#pragma unroll
  for (int n = 0; n < 4; ++n) {
    int c = n*16 + lrow;
    float b = bg[c];
#pragma unroll
    for (int m = 0; m < 2; ++m)
#pragma unroll
      for (int r = 0; r < 4; ++r) {
        int t = brow*128 + w*32 + m*16 + lk*4 + r;
        float logit = acc[m][n][r] + b;
        float gv = 1.0f / (1.0f + __expf(-logit));
        Aout[(size_t)t*KC + DIM + c] = f2bf(gv);
      }
  }
}

// ------------- Main GEMM: 256x256 tile, 8 waves (2x4), BK=32, 4-buf rotation,
// 2-phase-per-tile m201-style schedule: per phase {ds_read || stage -> bar ->
// lgkm(0) -> setprio MFMA x16 -> bar}, counted vmcnt(8) once per tile. -------------
__global__ __launch_bounds__(512, 2) void gemm_main8(const u16* __restrict__ A,
                                                     const u16* __restrict__ Bt,
                                                     const float* __restrict__ bu,
                                                     float* __restrict__ H) {
  __shared__ u16 AsB[4*8192];   // 4 bufs x 16 KiB
  __shared__ u16 BsB[4*8192];

  const int bid = blockIdx.x;
  const int wg  = (bid & 7) * (int)(gridDim.x >> 3) + (bid >> 3);  // XCD swizzle (1024%8==0)
  const int brow = wg >> 3;    // M/256 = 128 row tiles
  const int bcol = wg & 7;     // N/256 = 8 col tiles
  const int tid = threadIdx.x;
  const int w = tid >> 6, l = tid & 63;
  const int wm = w >> 2, wn = w & 3;       // 2 x 4 wave grid
  const int lrow = l & 15, lk = l >> 4;

  // Staging: linear LDS dest p; logical addr lp = p ^ swz(p-row-bits).
  // Swizzle (64B rows): byte ^= ((row&2)<<4) ^ ((row&4)<<2)
  const int p0 = tid * 16, p1 = 8192 + tid * 16;
  const int lp0 = p0 ^ (((p0 >> 7) & 1) << 5) ^ (((p0 >> 8) & 1) << 4);
  const int lp1 = p1 ^ (((p1 >> 7) & 1) << 5) ^ (((p1 >> 8) & 1) << 4);
  const int r0 = lp0 >> 6, c0 = (lp0 & 63) >> 1;
  const int r1 = lp1 >> 6, c1 = (lp1 & 63) >> 1;

  const u16* Asrc0 = A  + (size_t)(brow*256 + r0)*KC + c0;
  const u16* Asrc1 = A  + (size_t)(brow*256 + r1)*KC + c1;
  const u16* Bsrc0 = Bt + (size_t)(bcol*256 + r0)*KC + c0;
  const u16* Bsrc1 = Bt + (size_t)(bcol*256 + r1)*KC + c1;
  char* AsC = (char*)AsB;
  char* BsC = (char*)BsB;

  // Read-side physical byte offsets (same involution)
  const int asw = ((lrow & 2) << 4) | ((lrow & 4) << 2);
  int aoff[8], boff[4];
#pragma unroll
  for (int rf = 0; rf < 8; ++rf)
    aoff[rf] = (((wm*128 + rf*16 + lrow)*64) + lk*16) ^ asw;
#pragma unroll
  for (int cf = 0; cf < 4; ++cf)
    boff[cf] = (((wn*64 + cf*16 + lrow)*64) + lk*16) ^ asw;

  f32x4 acc[8][4] = {};

#define STAGE_A(kt) { const int bb_ = ((kt)&3)*16384; \
    GLDS16(Asrc0 + (size_t)(kt)*BK, AsC + bb_ + p0); \
    GLDS16(Asrc1 + (size_t)(kt)*BK, AsC + bb_ + p1); }
#define STAGE_B(kt) { const int bb_ = ((kt)&3)*16384; \
    GLDS16(Bsrc0 + (size_t)(kt)*BK, BsC + bb_ + p0); \
    GLDS16(Bsrc1 + (size_t)(kt)*BK, BsC + bb_ + p1); }

  // Prologue: stage tiles 0,1,2 (12 loads, tile-monotone order)
  STAGE_A(0); STAGE_B(0);
  STAGE_A(1); STAGE_B(1);
  STAGE_A(2); STAGE_B(2);
  asm volatile("s_waitcnt vmcnt(8)" ::: "memory");   // tile 0's 4 loads landed
  __builtin_amdgcn_sched_barrier(0);
  __builtin_amdgcn_s_barrier();

#pragma unroll 1
  for (int t = 0; t < NT; ++t) {
    const char* Ab = AsC + (t & 3) * 16384;
    const char* Bb = BsC + (t & 3) * 16384;

    // ---------------- phase 1: av[0..3] + bv[0..3]; stage A(t+3); MFMA rf 0..3
    bf16x8 a0 = *(const bf16x8*)(Ab + aoff[0]);
    bf16x8 a1 = *(const bf16x8*)(Ab + aoff[1]);
    bf16x8 a2 = *(const bf16x8*)(Ab + aoff[2]);
    bf16x8 a3 = *(const bf16x8*)(Ab + aoff[3]);
    bf16x8 b0 = *(const bf16x8*)(Bb + boff[0]);
    bf16x8 b1 = *(const bf16x8*)(Bb + boff[1]);
    bf16x8 b2 = *(const bf16x8*)(Bb + boff[2]);
    bf16x8 b3 = *(const bf16x8*)(Bb + boff[3]);
    if (t + 3 < NT) STAGE_A(t + 3);
    __builtin_amdgcn_s_barrier();
    asm volatile("s_waitcnt lgkmcnt(0)" ::: "memory");
    __builtin_amdgcn_sched_barrier(0);
    __builtin_amdgcn_s_setprio(1);
    acc[0][0] = __builtin_amdgcn_mfma_f32_16x16x32_bf16(a0, b0, acc[0][0], 0, 0, 0);
    acc[0][1] = __builtin_amdgcn_mfma_f32_16x16x32_bf16(a0, b1, acc[0][1], 0, 0, 0);
    acc[0][2] = __builtin_amdgcn_mfma_f32_16x16x32_bf16(a0, b2, acc[0][2], 0, 0, 0);
    acc[0][3] = __builtin_amdgcn_mfma_f32_16x16x32_bf16(a0, b3, acc[0][3], 0, 0, 0);
    acc[1][0] = __builtin_amdgcn_mfma_f32_16x16x32_bf16(a1, b0, acc[1][0], 0, 0, 0);
    acc[1][1] = __builtin_amdgcn_mfma_f32_16x16x32_bf16(a1, b1, acc[1][1], 0, 0, 0);
    acc[1][2] = __builtin_amdgcn_mfma_f32_16x16x32_bf16(a1, b2, acc[1][2], 0, 0, 0);
    acc[1][3] = __builtin_amdgcn_mfma_f32_16x16x32_bf16(a1, b3, acc[1][3], 0, 0, 0);
    acc[2][0] = __builtin_amdgcn_mfma_f32_16x16x32_bf16(a2, b0, acc[2][0], 0, 0, 0);
    acc[2][1] = __builtin_amdgcn_mfma_f32_16x16x32_bf16(a2, b1, acc[2][1], 0, 0, 0);
    acc[2][2] = __builtin_amdgcn_mfma_f32_16x16x32_bf16(a2, b2, acc[2][2], 0, 0, 0);
    acc[2][3] = __builtin_amdgcn_mfma_f32_16x16x32_bf16(a2, b3, acc[2][3], 0, 0, 0);
    acc[3][0] = __builtin_amdgcn_mfma_f32_16x16x32_bf16(a3, b0, acc[3][0], 0, 0, 0);
    acc[3][1] = __builtin_amdgcn_mfma_f32_16x16x32_bf16(a3, b1, acc[3][1], 0, 0, 0);
    acc[3][2] = __builtin_amdgcn_mfma_f32_16x16x32_bf16(a3, b2, acc[3][2], 0, 0, 0);
    acc[3][3] = __builtin_amdgcn_mfma_f32_16x16x32_bf16(a3, b3, acc[3][3], 0, 0, 0);
    __builtin_amdgcn_s_setprio(0);
    __builtin_amdgcn_s_barrier();

    // ---------------- phase 2: av[4..7]; stage B(t+3); MFMA rf 4..7
    bf16x8 a4 = *(const bf16x8*)(Ab + aoff[4]);
    bf16x8 a5 = *(const bf16x8*)(Ab + aoff[5]);
    bf16x8 a6 = *(const bf16x8*)(Ab + aoff[6]);
    bf16x8 a7 = *(const bf16x8*)(Ab + aoff[7]);
    if (t + 3 < NT) STAGE_B(t + 3);
    __builtin_amdgcn_s_barrier();
    asm volatile("s_waitcnt lgkmcnt(0)" ::: "memory");
    __builtin_amdgcn_sched_barrier(0);
    __builtin_amdgcn_s_setprio(1);
    acc[4][0] = __builtin_amdgcn_mfma_f32_16x16x32_bf16(a4, b0, acc[4][0], 0, 0, 0);
    acc[4][1] = __builtin_amdgcn_mfma_f32_16x16x32_bf16(a4, b1, acc[4][1], 0, 0, 0);
    acc[4][2] = __builtin_amdgcn_mfma_f32_16x16x32_bf16(a4, b2, acc[4][2], 0, 0, 0);
    acc[4][3] = __builtin_amdgcn_mfma_f32_16x16x32_bf16(a4, b3, acc[4][3], 0, 0, 0);
    acc[5][0] = __builtin_amdgcn_mfma_f32_16x16x32_bf16(a5, b0, acc[5][0], 0, 0, 0);
    acc[5][1] = __builtin_amdgcn_mfma_f32_16x16x32_bf16(a5, b1, acc[5][1], 0, 0, 0);
    acc[5][2] = __builtin_amdgcn_mfma_f32_16x16x32_bf16(a5, b2, acc[5][2], 0, 0, 0);
    acc[5][3] = __builtin_amdgcn_mfma_f32_16x16x32_bf16(a5, b3, acc[5][3], 0, 0, 0);
    acc[6][0] = __builtin_amdgcn_mfma_f32_16x16x32_bf16(a6, b0, acc[6][0], 0, 0, 0);
    acc[6][1] = __builtin_amdgcn_mfma_f32_16x16x32_bf16(a6, b1, acc[6][1], 0, 0, 0);
    acc[6][2] = __builtin_amdgcn_mfma_f32_16x16x32_bf16(a6, b2, acc[6][2], 0, 0, 0);
    acc[6][3] = __builtin_amdgcn_mfma_f32_16x16x32_bf16(a6, b3, acc[6][3], 0, 0, 0);
    acc[7][0] = __builtin_amdgcn_mfma_f32_16x16x32_bf16(a7, b0, acc[7][0], 0, 0, 0);
    acc[7][1] = __builtin_amdgcn_mfma_f32_16x16x32_bf16(a7, b1, acc[7][1], 0, 0, 0);
    acc[7][2] = __builtin_amdgcn_mfma_f32_16x16x32_bf16(a7, b2, acc[7][2], 0, 0, 0);
    acc[7][3] = __builtin_amdgcn_mfma_f32_16x16x32_bf16(a7, b3, acc[7][3], 0, 0, 0);
    __builtin_amdgcn_s_setprio(0);
    // tile boundary: counted vmcnt so tile t+1's 4 loads are visible after bar
    if (t <= NT-4)      { asm volatile("s_waitcnt vmcnt(8)" ::: "memory"); }
    else if (t == NT-3) { asm volatile("s_waitcnt vmcnt(4)" ::: "memory"); }
    else                { asm volatile("s_waitcnt vmcnt(0)" ::: "memory"); }
    __builtin_amdgcn_sched_barrier(0);
    __builtin_amdgcn_s_barrier();
  }
#undef STAGE_A
#undef STAGE_B

  const int orow = brow*256 + wm*128 + lk*4;
  const int ocol = bcol*256 + wn*64 + lrow;
#pragma unroll
  for (int cf = 0; cf < 4; ++cf) {
    const int c = ocol + cf*16;
    const float bias = bu[c];
#pragma unroll
    for (int rf = 0; rf < 8; ++rf) {
      const int rr = orow + rf*16;
#pragma unroll
      for (int r = 0; r < 4; ++r)
        H[(size_t)(rr + r)*DIM + c] = acc[rf][cf][r] + bias;
    }
  }
}

// ---------------- LN (in-place on d_out) ----------------
__global__ __launch_bounds__(256) void ln_inplace(float* __restrict__ H,
                                                  const float* __restrict__ gamma,
                                                  const float* __restrict__ beta) {
  int row = blockIdx.x;
  float* h = H + (size_t)row*DIM;
  int tid = threadIdx.x;
  float4 a = reinterpret_cast<const float4*>(h)[tid*2];
  float4 b = reinterpret_cast<const float4*>(h)[tid*2+1];
  float v[8] = {a.x,a.y,a.z,a.w,b.x,b.y,b.z,b.w};
  float s = 0.f, s2 = 0.f;
#pragma unroll
  for (int j = 0; j < 8; ++j) { s += v[j]; s2 += v[j]*v[j]; }
#pragma unroll
  for (int o = 32; o >= 1; o >>= 1) { s += __shfl_xor(s, o); s2 += __shfl_xor(s2, o); }
  __shared__ float ss[4], ss2[4];
  int w = tid >> 6;
  if ((tid & 63) == 0) { ss[w] = s; ss2[w] = s2; }
  __syncthreads();
  s  = ss[0]+ss[1]+ss[2]+ss[3];
  s2 = ss2[0]+ss2[1]+ss2[2]+ss2[3];
  float mu  = s * (1.0f/DIM);
  float var = s2 * (1.0f/DIM) - mu*mu;
  float rs  = rsqrtf(var + 1e-5f);
  int c0 = tid*8;
  float o8[8];
#pragma unroll
  for (int j = 0; j < 8; ++j) o8[j] = (v[j]-mu)*rs*gamma[c0+j] + beta[c0+j];
  float4 oa = {o8[0],o8[1],o8[2],o8[3]}, ob = {o8[4],o8[5],o8[6],o8[7]};
  reinterpret_cast<float4*>(h)[tid*2]   = oa;
  reinterpret_cast<float4*>(h)[tid*2+1] = ob;
}

extern "C" void kernel_launch(void* const* d_in, const int* in_sizes, int n_in,
                              void* d_out, int out_size, void* d_ws, size_t ws_size,
                              hipStream_t stream) {
  const float* x     = (const float*)d_in[0];
  const float* ms    = (const float*)d_in[1];
  const float* Wg    = (const float*)d_in[2];
  const float* bg    = (const float*)d_in[3];
  const float* Wu    = (const float*)d_in[4];
  const float* bu    = (const float*)d_in[5];
  const float* gamma = (const float*)d_in[6];
  const float* beta  = (const float*)d_in[7];
  float* out = (float*)d_out;

  char* wsp = (char*)d_ws;
  u16* Acat  = (u16*)wsp;                                                 // 138,412,032 B
  u16* WcatT = (u16*)(wsp + (size_t)MTOK*KC*2);                           // 8,650,752 B
  u16* WgT   = (u16*)(wsp + (size_t)MTOK*KC*2 + (size_t)DIM*KC*2);        // 262,144 B
  float* M2p = (float*)wsp;  // 4 MiB partials, aliases Acat (consumed before conv_x)

  prep_m2a<<<dim3(8,16,8), 256, 0, stream>>>(ms, Wu, M2p);
  prep_m2b<<<512, 256, 0, stream>>>(M2p, WcatT);
  prep_wu1<<<1024, 256, 0, stream>>>(Wu, WcatT);
  prep_wg<<<32, 256, 0, stream>>>(Wg, WgT);
  conv_x<<<32768, 256, 0, stream>>>(x, Acat);
  gates_gemm<<<256, 256, 0, stream>>>(Acat, WgT, bg, Acat);
  gemm_main8<<<1024, 512, 0, stream>>>(Acat, WcatT, bu, out);
  ln_inplace<<<32768, 256, 0, stream>>>(out, gamma, beta);
}

// Round 5
// 578.587 us; speedup vs baseline: 1.2993x; 1.0075x over previous
//
#include <hip/hip_runtime.h>
#include <hip/hip_bf16.h>

typedef __bf16 bf16x8 __attribute__((ext_vector_type(8)));
typedef float f32x4 __attribute__((ext_vector_type(4)));
typedef float f32x16 __attribute__((ext_vector_type(16)));
typedef unsigned short u16;
typedef u16 u16x8 __attribute__((ext_vector_type(8)));

#define DIM 2048
#define MEM 64
#define KC 2112   /* 2048 + 64 concatenated K */
#define MTOK 32768
#define BK 32
#define NT (KC/BK)   /* 66 K-tiles */

__device__ __forceinline__ u16 f2bf(float f) {
  union { float f; unsigned u; } v; v.f = f;
  unsigned r = v.u + 0x7FFF + ((v.u >> 16) & 1);  // RNE
  return (u16)(r >> 16);
}

#define GLDS16(g, l) __builtin_amdgcn_global_load_lds( \
    (const __attribute__((address_space(1))) void*)(g), \
    (__attribute__((address_space(3))) void*)(l), 16, 0, 0)

// ---------------- P1: WcatT[n][k] = bf16(Wu[k][n]) for k < 2048 ----------------
__global__ __launch_bounds__(256) void prep_wu1(const float* __restrict__ Wu,
                                                u16* __restrict__ WcatT) {
  __shared__ float tile[64][65];
  int bk = blockIdx.x & 31;   // k-tile (2048/64)
  int bn = blockIdx.x >> 5;   // n-tile (2048/64)
  int tx = threadIdx.x & 63, g = threadIdx.x >> 6;
#pragma unroll
  for (int i = 0; i < 16; ++i)
    tile[g + i*4][tx] = Wu[(size_t)(bk*64 + g + i*4)*DIM + bn*64 + tx];
  __syncthreads();
#pragma unroll
  for (int i = 0; i < 16; ++i) {
    int n = bn*64 + g + i*4;
    WcatT[(size_t)n*KC + bk*64 + tx] = f2bf(tile[tx][g + i*4]);
  }
}

// ------- P2a: split-K partials of M2 = ms @ Wu2 (deterministic, no atomics) -------
__global__ __launch_bounds__(256) void prep_m2a(const float* __restrict__ ms,
                                                const float* __restrict__ Wu,
                                                float* __restrict__ M2p) {
  int n  = blockIdx.x*256 + threadIdx.x;   // 8 blocks
  int mg = blockIdx.y;                     // 16 groups of 4 m
  int kc = blockIdx.z;                     // 8 k-chunks of 256
  const float* w2 = Wu + (size_t)DIM*DIM + n;
  const float* m0 = ms + (size_t)(mg*4+0)*DIM;
  const float* m1 = ms + (size_t)(mg*4+1)*DIM;
  const float* m2 = ms + (size_t)(mg*4+2)*DIM;
  const float* m3 = ms + (size_t)(mg*4+3)*DIM;
  float a0=0.f, a1=0.f, a2=0.f, a3=0.f;
  int d0 = kc*256;
  for (int d = d0; d < d0+256; ++d) {
    float w = w2[(size_t)d*DIM];
    a0 += m0[d]*w; a1 += m1[d]*w; a2 += m2[d]*w; a3 += m3[d]*w;
  }
  M2p[((size_t)kc*64 + mg*4 + 0)*2048 + n] = a0;
  M2p[((size_t)kc*64 + mg*4 + 1)*2048 + n] = a1;
  M2p[((size_t)kc*64 + mg*4 + 2)*2048 + n] = a2;
  M2p[((size_t)kc*64 + mg*4 + 3)*2048 + n] = a3;
}

// ------- P2b: reduce partials -> WcatT[n][2048+m] -------
__global__ __launch_bounds__(256) void prep_m2b(const float* __restrict__ M2p,
                                                u16* __restrict__ WcatT) {
  int i = blockIdx.x*256 + threadIdx.x;    // 512 blocks, i = m*2048 + n
  float s = 0.f;
#pragma unroll
  for (int kc = 0; kc < 8; ++kc) s += M2p[(size_t)kc*131072 + i];
  int m = i >> 11, n = i & 2047;
  WcatT[(size_t)n*KC + DIM + m] = f2bf(s);
}

// ---------------- P3: WgT[m][k] = bf16(Wg[k][m]) ----------------
__global__ __launch_bounds__(256) void prep_wg(const float* __restrict__ Wg,
                                               u16* __restrict__ WgT) {
  __shared__ float tile[64][65];
  int k0 = blockIdx.x * 64;
  int tx = threadIdx.x & 63, g = threadIdx.x >> 6;
#pragma unroll
  for (int i = 0; i < 16; ++i)
    tile[g + i*4][tx] = Wg[(size_t)(k0 + g + i*4)*MEM + tx];
  __syncthreads();
#pragma unroll
  for (int i = 0; i < 16; ++i) {
    int m = g + i*4;
    WgT[(size_t)m*DIM + k0 + tx] = f2bf(tile[tx][m]);
  }
}

// ---------------- A1: Acat[t][0:2048] = bf16(x[t][:]) ----------------
__global__ __launch_bounds__(256) void conv_x(const float* __restrict__ x,
                                              u16* __restrict__ Acat) {
  size_t i = ((size_t)blockIdx.x*256 + threadIdx.x) * 8;
  size_t t = i >> 11;
  int c = (int)(i & 2047);
  const float4* p = reinterpret_cast<const float4*>(x + i);
  float4 a = p[0], b = p[1];
  u16x8 o;
  o[0]=f2bf(a.x); o[1]=f2bf(a.y); o[2]=f2bf(a.z); o[3]=f2bf(a.w);
  o[4]=f2bf(b.x); o[5]=f2bf(b.y); o[6]=f2bf(b.z); o[7]=f2bf(b.w);
  *reinterpret_cast<u16x8*>(Acat + t*KC + c) = o;
}

// ------- A2: Acat[t][2048+c] = bf16(sigmoid(X@Wg + bg)), MFMA mini-GEMM -------
__global__ __launch_bounds__(256) void gates_gemm(const u16* __restrict__ Acat,
                                                  const u16* __restrict__ WgT,
                                                  const float* __restrict__ bg,
                                                  u16* __restrict__ Aout) {
  __shared__ u16 As[128*32];
  __shared__ u16 Bs[64*32];
  int brow = blockIdx.x;
  int tid = threadIdx.x;
  int w = tid >> 6, l = tid & 63;
  int lrow = l & 15, lk = l >> 4;

  const u16* Ag  = Acat + (size_t)(brow*128 + (tid>>2))*KC + (tid&3)*8;
  const u16* Ag2 = Acat + (size_t)(brow*128 + 64 + (tid>>2))*KC + (tid&3)*8;
  const u16* Bg  = WgT  + (size_t)(tid>>2)*DIM + (tid&3)*8;
  u16* Asd  = As + tid*8;
  u16* Asd2 = As + 2048 + tid*8;
  u16* Bsd  = Bs + tid*8;

  f32x4 acc[2][4] = {};
  const bf16x8* Al = reinterpret_cast<const bf16x8*>(As);
  const bf16x8* Bl = reinterpret_cast<const bf16x8*>(Bs);
  int abase = (w*32 + lrow)*4 + lk;
  int bbase = lrow*4 + lk;

  for (int k0 = 0; k0 < DIM; k0 += 32) {
    GLDS16(Ag, Asd); GLDS16(Ag2, Asd2); GLDS16(Bg, Bsd);
    Ag += 32; Ag2 += 32; Bg += 32;
    __syncthreads();
    bf16x8 av[2], bv[4];
#pragma unroll
    for (int m = 0; m < 2; ++m) av[m] = Al[abase + m*64];
#pragma unroll
    for (int n = 0; n < 4; ++n) bv[n] = Bl[bbase + n*64];
#pragma unroll
    for (int m = 0; m < 2; ++m)
#pragma unroll
      for (int n = 0; n < 4; ++n)
        acc[m][n] = __builtin_amdgcn_mfma_f32_16x16x32_bf16(av[m], bv[n], acc[m][n], 0, 0, 0);
    __syncthreads();
  }

#pragma unroll
  for (int n = 0; n < 4; ++n) {
    int c = n*16 + lrow;
    float b = bg[c];
#pragma unroll
    for (int m = 0; m < 2; ++m)
#pragma unroll
      for (int r = 0; r < 4; ++r) {
        int t = brow*128 + w*32 + m*16 + lk*4 + r;
        float logit = acc[m][n][r] + b;
        float gv = 1.0f / (1.0f + __expf(-logit));
        Aout[(size_t)t*KC + DIM + c] = f2bf(gv);
      }
  }
}

// ------------- Main GEMM: 256x256 tile, 8 waves (2x4), BK=32, 4-buf rotation,
// 32x32x16 MFMA, m201 st_16x32 swizzle (byte ^= ((byte>>9)&1)<<5), 2 phases/tile,
// counted vmcnt(8), setprio. H = Acat @ WcatT^T + bu (fp32) -------------
__global__ __launch_bounds__(512, 2) void gemm_main8(const u16* __restrict__ A,
                                                     const u16* __restrict__ Bt,
                                                     const float* __restrict__ bu,
                                                     float* __restrict__ H) {
  __shared__ u16 AsB[4*8192];   // 4 bufs x 16 KiB
  __shared__ u16 BsB[4*8192];

  const int bid = blockIdx.x;
  const int wg  = (bid & 7) * (int)(gridDim.x >> 3) + (bid >> 3);  // XCD swizzle (1024%8==0)
  const int brow = wg >> 3;    // M/256 = 128 row tiles
  const int bcol = wg & 7;     // N/256 = 8 col tiles
  const int tid = threadIdx.x;
  const int w = tid >> 6, l = tid & 63;
  const int wm = w >> 2, wn = w & 3;       // 2 x 4 wave grid
  const int l31 = l & 31, lr5 = l >> 5;

  // ---- staging (write side): linear phys dest p = tid*16 (+8192 for half 1);
  // logical = phys ^ ((phys>>9&1)<<5); bit9 = row bit 3 (row = byte>>6).
  const int xor5  = ((tid >> 5) & 1) << 5;                 // row bit3 of tid>>2
  const int kelem = (((tid & 3) * 16) ^ xor5) >> 1;        // 0..31 (16B-aligned)
  const int rowst = tid >> 2;                              // 0..127
  const u16* Asrc0 = A  + (size_t)(brow*256 + rowst)*KC + kelem;
  const u16* Asrc1 = A  + (size_t)(brow*256 + 128 + rowst)*KC + kelem;
  const u16* Bsrc0 = Bt + (size_t)(bcol*256 + rowst)*KC + kelem;
  const u16* Bsrc1 = Bt + (size_t)(bcol*256 + 128 + rowst)*KC + kelem;
  const int p0 = tid*16, p1 = 8192 + tid*16;
  char* AsC = (char*)AsB;
  char* BsC = (char*)BsB;

  // ---- read offsets (32x32x16 frags): lane -> row = base + (l&31),
  // k = lr5*8 + j (16B b128). phys = log ^ ((row>>3&1)<<5).
  int aoff[4][2], boff[2][2];
#pragma unroll
  for (int rf = 0; rf < 4; ++rf)
#pragma unroll
    for (int ks = 0; ks < 2; ++ks) {
      int row = wm*128 + rf*32 + l31;
      int lg  = row*64 + ks*32 + lr5*16;
      aoff[rf][ks] = lg ^ (((row >> 3) & 1) << 5);
    }
#pragma unroll
  for (int cf = 0; cf < 2; ++cf)
#pragma unroll
    for (int ks = 0; ks < 2; ++ks) {
      int row = wn*64 + cf*32 + l31;
      int lg  = row*64 + ks*32 + lr5*16;
      boff[cf][ks] = lg ^ (((row >> 3) & 1) << 5);
    }

  f32x16 acc[4][2] = {};

#define STAGE_A(kt) { const int bb_ = ((kt)&3)*16384; \
    GLDS16(Asrc0 + (size_t)(kt)*BK, AsC + bb_ + p0); \
    GLDS16(Asrc1 + (size_t)(kt)*BK, AsC + bb_ + p1); }
#define STAGE_B(kt) { const int bb_ = ((kt)&3)*16384; \
    GLDS16(Bsrc0 + (size_t)(kt)*BK, BsC + bb_ + p0); \
    GLDS16(Bsrc1 + (size_t)(kt)*BK, BsC + bb_ + p1); }
#define MFMA32(av, bv, c) __builtin_amdgcn_mfma_f32_32x32x16_bf16(av, bv, c, 0, 0, 0)

  // Prologue: stage tiles 0,1,2 (12 loads)
  STAGE_A(0); STAGE_B(0);
  STAGE_A(1); STAGE_B(1);
  STAGE_A(2); STAGE_B(2);
  asm volatile("s_waitcnt vmcnt(8)" ::: "memory");   // tile 0's 4 loads landed
  __builtin_amdgcn_sched_barrier(0);
  __builtin_amdgcn_s_barrier();

#pragma unroll 1
  for (int t = 0; t < NT; ++t) {
    const char* Ab = AsC + (t & 3) * 16384;
    const char* Bb = BsC + (t & 3) * 16384;

    // ---------------- phase 1: B all + A rf0-1; stage A(t+3); 8 MFMA
    bf16x8 b00 = *(const bf16x8*)(Bb + boff[0][0]);
    bf16x8 b01 = *(const bf16x8*)(Bb + boff[0][1]);
    bf16x8 b10 = *(const bf16x8*)(Bb + boff[1][0]);
    bf16x8 b11 = *(const bf16x8*)(Bb + boff[1][1]);
    bf16x8 a00 = *(const bf16x8*)(Ab + aoff[0][0]);
    bf16x8 a01 = *(const bf16x8*)(Ab + aoff[0][1]);
    bf16x8 a10 = *(const bf16x8*)(Ab + aoff[1][0]);
    bf16x8 a11 = *(const bf16x8*)(Ab + aoff[1][1]);
    if (t + 3 < NT) STAGE_A(t + 3);
    __builtin_amdgcn_s_barrier();
    asm volatile("s_waitcnt lgkmcnt(0)" ::: "memory");
    __builtin_amdgcn_sched_barrier(0);
    __builtin_amdgcn_s_setprio(1);
    acc[0][0] = MFMA32(a00, b00, acc[0][0]);
    acc[0][1] = MFMA32(a00, b10, acc[0][1]);
    acc[1][0] = MFMA32(a10, b00, acc[1][0]);
    acc[1][1] = MFMA32(a10, b10, acc[1][1]);
    acc[0][0] = MFMA32(a01, b01, acc[0][0]);
    acc[0][1] = MFMA32(a01, b11, acc[0][1]);
    acc[1][0] = MFMA32(a11, b01, acc[1][0]);
    acc[1][1] = MFMA32(a11, b11, acc[1][1]);
    __builtin_amdgcn_s_setprio(0);
    __builtin_amdgcn_s_barrier();

    // ---------------- phase 2: A rf2-3; stage B(t+3); 8 MFMA
    bf16x8 a20 = *(const bf16x8*)(Ab + aoff[2][0]);
    bf16x8 a21 = *(const bf16x8*)(Ab + aoff[2][1]);
    bf16x8 a30 = *(const bf16x8*)(Ab + aoff[3][0]);
    bf16x8 a31 = *(const bf16x8*)(Ab + aoff[3][1]);
    if (t + 3 < NT) STAGE_B(t + 3);
    __builtin_amdgcn_s_barrier();
    asm volatile("s_waitcnt lgkmcnt(0)" ::: "memory");
    __builtin_amdgcn_sched_barrier(0);
    __builtin_amdgcn_s_setprio(1);
    acc[2][0] = MFMA32(a20, b00, acc[2][0]);
    acc[2][1] = MFMA32(a20, b10, acc[2][1]);
    acc[3][0] = MFMA32(a30, b00, acc[3][0]);
    acc[3][1] = MFMA32(a30, b10, acc[3][1]);
    acc[2][0] = MFMA32(a21, b01, acc[2][0]);
    acc[2][1] = MFMA32(a21, b11, acc[2][1]);
    acc[3][0] = MFMA32(a31, b01, acc[3][0]);
    acc[3][1] = MFMA32(a31, b11, acc[3][1]);
    __builtin_amdgcn_s_setprio(0);
    // tile boundary: counted vmcnt so tile t+1's 4 loads are visible after bar
    if (t <= NT-4)      { asm volatile("s_waitcnt vmcnt(8)" ::: "memory"); }
    else if (t == NT-3) { asm volatile("s_waitcnt vmcnt(4)" ::: "memory"); }
    else                { asm volatile("s_waitcnt vmcnt(0)" ::: "memory"); }
    __builtin_amdgcn_sched_barrier(0);
    __builtin_amdgcn_s_barrier();
  }
#undef STAGE_A
#undef STAGE_B
#undef MFMA32

  // Epilogue: C-layout 32x32: col = l&31, row = (reg&3) + 8*(reg>>2) + 4*lr5
  const int orow = brow*256 + wm*128;
  const int ocol = bcol*256 + wn*64;
#pragma unroll
  for (int cf = 0; cf < 2; ++cf) {
    const int c = ocol + cf*32 + l31;
    const float bias = bu[c];
#pragma unroll
    for (int rf = 0; rf < 4; ++rf) {
      const int br = orow + rf*32 + 4*lr5;
#pragma unroll
      for (int reg = 0; reg < 16; ++reg) {
        const int row = br + (reg & 3) + 8*(reg >> 2);
        H[(size_t)row*DIM + c] = acc[rf][cf][reg] + bias;
      }
    }
  }
}

// ---------------- LN (in-place on d_out) ----------------
__global__ __launch_bounds__(256) void ln_inplace(float* __restrict__ H,
                                                  const float* __restrict__ gamma,
                                                  const float* __restrict__ beta) {
  int row = blockIdx.x;
  float* h = H + (size_t)row*DIM;
  int tid = threadIdx.x;
  float4 a = reinterpret_cast<const float4*>(h)[tid*2];
  float4 b = reinterpret_cast<const float4*>(h)[tid*2+1];
  float v[8] = {a.x,a.y,a.z,a.w,b.x,b.y,b.z,b.w};
  float s = 0.f, s2 = 0.f;
#pragma unroll
  for (int j = 0; j < 8; ++j) { s += v[j]; s2 += v[j]*v[j]; }
#pragma unroll
  for (int o = 32; o >= 1; o >>= 1) { s += __shfl_xor(s, o); s2 += __shfl_xor(s2, o); }
  __shared__ float ss[4], ss2[4];
  int w = tid >> 6;
  if ((tid & 63) == 0) { ss[w] = s; ss2[w] = s2; }
  __syncthreads();
  s  = ss[0]+ss[1]+ss[2]+ss[3];
  s2 = ss2[0]+ss2[1]+ss2[2]+ss2[3];
  float mu  = s * (1.0f/DIM);
  float var = s2 * (1.0f/DIM) - mu*mu;
  float rs  = rsqrtf(var + 1e-5f);
  int c0 = tid*8;
  float o8[8];
#pragma unroll
  for (int j = 0; j < 8; ++j) o8[j] = (v[j]-mu)*rs*gamma[c0+j] + beta[c0+j];
  float4 oa = {o8[0],o8[1],o8[2],o8[3]}, ob = {o8[4],o8[5],o8[6],o8[7]};
  reinterpret_cast<float4*>(h)[tid*2]   = oa;
  reinterpret_cast<float4*>(h)[tid*2+1] = ob;
}

extern "C" void kernel_launch(void* const* d_in, const int* in_sizes, int n_in,
                              void* d_out, int out_size, void* d_ws, size_t ws_size,
                              hipStream_t stream) {
  const float* x     = (const float*)d_in[0];
  const float* ms    = (const float*)d_in[1];
  const float* Wg    = (const float*)d_in[2];
  const float* bg    = (const float*)d_in[3];
  const float* Wu    = (const float*)d_in[4];
  const float* bu    = (const float*)d_in[5];
  const float* gamma = (const float*)d_in[6];
  const float* beta  = (const float*)d_in[7];
  float* out = (float*)d_out;

  char* wsp = (char*)d_ws;
  u16* Acat  = (u16*)wsp;                                                 // 138,412,032 B
  u16* WcatT = (u16*)(wsp + (size_t)MTOK*KC*2);                           // 8,650,752 B
  u16* WgT   = (u16*)(wsp + (size_t)MTOK*KC*2 + (size_t)DIM*KC*2);        // 262,144 B
  float* M2p = (float*)wsp;  // 4 MiB partials, aliases Acat (consumed before conv_x)

  prep_m2a<<<dim3(8,16,8), 256, 0, stream>>>(ms, Wu, M2p);
  prep_m2b<<<512, 256, 0, stream>>>(M2p, WcatT);
  prep_wu1<<<1024, 256, 0, stream>>>(Wu, WcatT);
  prep_wg<<<32, 256, 0, stream>>>(Wg, WgT);
  conv_x<<<32768, 256, 0, stream>>>(x, Acat);
  gates_gemm<<<256, 256, 0, stream>>>(Acat, WgT, bg, Acat);
  gemm_main8<<<1024, 512, 0, stream>>>(Acat, WcatT, bu, out);
  ln_inplace<<<32768, 256, 0, stream>>>(out, gamma, beta);
}

// Round 6
// 513.222 us; speedup vs baseline: 1.4647x; 1.1274x over previous
//
#include <hip/hip_runtime.h>
#include <hip/hip_bf16.h>

typedef __bf16 bf16x8 __attribute__((ext_vector_type(8)));
typedef float f32x4 __attribute__((ext_vector_type(4)));
typedef float f32x16 __attribute__((ext_vector_type(16)));
typedef unsigned short u16;
typedef u16 u16x8 __attribute__((ext_vector_type(8)));

#define DIM 2048
#define MEM 64
#define KC 2112   /* 2048 + 64 concatenated K */
#define MTOK 32768
#define BK 32
#define NT (KC/BK)   /* 66 K-tiles */

__device__ __forceinline__ u16 f2bf(float f) {
  union { float f; unsigned u; } v; v.f = f;
  unsigned r = v.u + 0x7FFF + ((v.u >> 16) & 1);  // RNE
  return (u16)(r >> 16);
}
__device__ __forceinline__ float bf2f(u16 u) {
  union { unsigned u; float f; } v; v.u = ((unsigned)u) << 16; return v.f;
}

#define GLDS16(g, l) __builtin_amdgcn_global_load_lds( \
    (const __attribute__((address_space(1))) void*)(g), \
    (__attribute__((address_space(3))) void*)(l), 16, 0, 0)

// ---------------- P1: WcatT[n][k] = bf16(Wu[k][n]) for k < 2048 ----------------
__global__ __launch_bounds__(256) void prep_wu1(const float* __restrict__ Wu,
                                                u16* __restrict__ WcatT) {
  __shared__ float tile[64][65];
  int bk = blockIdx.x & 31;
  int bn = blockIdx.x >> 5;
  int tx = threadIdx.x & 63, g = threadIdx.x >> 6;
#pragma unroll
  for (int i = 0; i < 16; ++i)
    tile[g + i*4][tx] = Wu[(size_t)(bk*64 + g + i*4)*DIM + bn*64 + tx];
  __syncthreads();
#pragma unroll
  for (int i = 0; i < 16; ++i) {
    int n = bn*64 + g + i*4;
    WcatT[(size_t)n*KC + bk*64 + tx] = f2bf(tile[tx][g + i*4]);
  }
}

// ------- P2a: split-K partials of M2 = ms @ Wu2 -------
__global__ __launch_bounds__(256) void prep_m2a(const float* __restrict__ ms,
                                                const float* __restrict__ Wu,
                                                float* __restrict__ M2p) {
  int n  = blockIdx.x*256 + threadIdx.x;
  int mg = blockIdx.y;
  int kc = blockIdx.z;
  const float* w2 = Wu + (size_t)DIM*DIM + n;
  const float* m0 = ms + (size_t)(mg*4+0)*DIM;
  const float* m1 = ms + (size_t)(mg*4+1)*DIM;
  const float* m2 = ms + (size_t)(mg*4+2)*DIM;
  const float* m3 = ms + (size_t)(mg*4+3)*DIM;
  float a0=0.f, a1=0.f, a2=0.f, a3=0.f;
  int d0 = kc*256;
  for (int d = d0; d < d0+256; ++d) {
    float w = w2[(size_t)d*DIM];
    a0 += m0[d]*w; a1 += m1[d]*w; a2 += m2[d]*w; a3 += m3[d]*w;
  }
  M2p[((size_t)kc*64 + mg*4 + 0)*2048 + n] = a0;
  M2p[((size_t)kc*64 + mg*4 + 1)*2048 + n] = a1;
  M2p[((size_t)kc*64 + mg*4 + 2)*2048 + n] = a2;
  M2p[((size_t)kc*64 + mg*4 + 3)*2048 + n] = a3;
}

// ------- P2b: reduce partials -> WcatT[n][2048+m] -------
__global__ __launch_bounds__(256) void prep_m2b(const float* __restrict__ M2p,
                                                u16* __restrict__ WcatT) {
  int i = blockIdx.x*256 + threadIdx.x;
  float s = 0.f;
#pragma unroll
  for (int kc = 0; kc < 8; ++kc) s += M2p[(size_t)kc*131072 + i];
  int m = i >> 11, n = i & 2047;
  WcatT[(size_t)n*KC + DIM + m] = f2bf(s);
}

// ---------------- P3: WgT[m][k] = bf16(Wg[k][m]) ----------------
__global__ __launch_bounds__(256) void prep_wg(const float* __restrict__ Wg,
                                               u16* __restrict__ WgT) {
  __shared__ float tile[64][65];
  int k0 = blockIdx.x * 64;
  int tx = threadIdx.x & 63, g = threadIdx.x >> 6;
#pragma unroll
  for (int i = 0; i < 16; ++i)
    tile[g + i*4][tx] = Wg[(size_t)(k0 + g + i*4)*MEM + tx];
  __syncthreads();
#pragma unroll
  for (int i = 0; i < 16; ++i) {
    int m = g + i*4;
    WgT[(size_t)m*DIM + k0 + tx] = f2bf(tile[tx][m]);
  }
}

// ---------------- A1: Acat[t][0:2048] = bf16(x[t][:]) ----------------
__global__ __launch_bounds__(256) void conv_x(const float* __restrict__ x,
                                              u16* __restrict__ Acat) {
  size_t i = ((size_t)blockIdx.x*256 + threadIdx.x) * 8;
  size_t t = i >> 11;
  int c = (int)(i & 2047);
  const float4* p = reinterpret_cast<const float4*>(x + i);
  float4 a = p[0], b = p[1];
  u16x8 o;
  o[0]=f2bf(a.x); o[1]=f2bf(a.y); o[2]=f2bf(a.z); o[3]=f2bf(a.w);
  o[4]=f2bf(b.x); o[5]=f2bf(b.y); o[6]=f2bf(b.z); o[7]=f2bf(b.w);
  *reinterpret_cast<u16x8*>(Acat + t*KC + c) = o;
}

// ------- A2: Acat[t][2048+c] = bf16(sigmoid(X@Wg + bg)) -------
__global__ __launch_bounds__(256) void gates_gemm(const u16* __restrict__ Acat,
                                                  const u16* __restrict__ WgT,
                                                  const float* __restrict__ bg,
                                                  u16* __restrict__ Aout) {
  __shared__ u16 As[128*32];
  __shared__ u16 Bs[64*32];
  int brow = blockIdx.x;
  int tid = threadIdx.x;
  int w = tid >> 6, l = tid & 63;
  int lrow = l & 15, lk = l >> 4;

  const u16* Ag  = Acat + (size_t)(brow*128 + (tid>>2))*KC + (tid&3)*8;
  const u16* Ag2 = Acat + (size_t)(brow*128 + 64 + (tid>>2))*KC + (tid&3)*8;
  const u16* Bg  = WgT  + (size_t)(tid>>2)*DIM + (tid&3)*8;
  u16* Asd  = As + tid*8;
  u16* Asd2 = As + 2048 + tid*8;
  u16* Bsd  = Bs + tid*8;

  f32x4 acc[2][4] = {};
  const bf16x8* Al = reinterpret_cast<const bf16x8*>(As);
  const bf16x8* Bl = reinterpret_cast<const bf16x8*>(Bs);
  int abase = (w*32 + lrow)*4 + lk;
  int bbase = lrow*4 + lk;

  for (int k0 = 0; k0 < DIM; k0 += 32) {
    GLDS16(Ag, Asd); GLDS16(Ag2, Asd2); GLDS16(Bg, Bsd);
    Ag += 32; Ag2 += 32; Bg += 32;
    __syncthreads();
    bf16x8 av[2], bv[4];
#pragma unroll
    for (int m = 0; m < 2; ++m) av[m] = Al[abase + m*64];
#pragma unroll
    for (int n = 0; n < 4; ++n) bv[n] = Bl[bbase + n*64];
#pragma unroll
    for (int m = 0; m < 2; ++m)
#pragma unroll
      for (int n = 0; n < 4; ++n)
        acc[m][n] = __builtin_amdgcn_mfma_f32_16x16x32_bf16(av[m], bv[n], acc[m][n], 0, 0, 0);
    __syncthreads();
  }

#pragma unroll
  for (int n = 0; n < 4; ++n) {
    int c = n*16 + lrow;
    float b = bg[c];
#pragma unroll
    for (int m = 0; m < 2; ++m)
#pragma unroll
      for (int r = 0; r < 4; ++r) {
        int t = brow*128 + w*32 + m*16 + lk*4 + r;
        float logit = acc[m][n][r] + b;
        float gv = 1.0f / (1.0f + __expf(-logit));
        Aout[(size_t)t*KC + DIM + c] = f2bf(gv);
      }
  }
}

// ------------- Main GEMM: 256x256 tile, 8 waves (2x4), BK=32, 4-buf depth-3,
// 32x32x16 MFMA, m201 swizzle, ONE barrier + ONE counted vmcnt per tile,
// compiler-managed lgkm, ks-balanced phases (8 independent MFMA each). -------------
__global__ __launch_bounds__(512, 2) void gemm_main8(const u16* __restrict__ A,
                                                     const u16* __restrict__ Bt,
                                                     const float* __restrict__ bu,
                                                     float* __restrict__ Hf,
                                                     u16* __restrict__ Hb) {
  __shared__ u16 AsB[4*8192];   // 4 bufs x 16 KiB
  __shared__ u16 BsB[4*8192];

  const int bid = blockIdx.x;
  const int wg  = (bid & 7) * (int)(gridDim.x >> 3) + (bid >> 3);  // XCD swizzle
  const int brow = wg >> 3;
  const int bcol = wg & 7;
  const int tid = threadIdx.x;
  const int w = tid >> 6, l = tid & 63;
  const int wm = w >> 2, wn = w & 3;
  const int l31 = l & 31, lr5 = l >> 5;

  // staging: linear phys dest, pre-swizzled global source (m201 st_16x32)
  const int xor5  = ((tid >> 5) & 1) << 5;
  const int kelem = (((tid & 3) * 16) ^ xor5) >> 1;
  const int rowst = tid >> 2;
  const u16* Asrc0 = A  + (size_t)(brow*256 + rowst)*KC + kelem;
  const u16* Asrc1 = A  + (size_t)(brow*256 + 128 + rowst)*KC + kelem;
  const u16* Bsrc0 = Bt + (size_t)(bcol*256 + rowst)*KC + kelem;
  const u16* Bsrc1 = Bt + (size_t)(bcol*256 + 128 + rowst)*KC + kelem;
  const int p0 = tid*16, p1 = 8192 + tid*16;
  char* AsC = (char*)AsB;
  char* BsC = (char*)BsB;

  // read offsets (32x32x16 frags), same involution
  int aoff[4][2], boff[2][2];
#pragma unroll
  for (int rf = 0; rf < 4; ++rf)
#pragma unroll
    for (int ks = 0; ks < 2; ++ks) {
      int row = wm*128 + rf*32 + l31;
      int lg  = row*64 + ks*32 + lr5*16;
      aoff[rf][ks] = lg ^ (((row >> 3) & 1) << 5);
    }
#pragma unroll
  for (int cf = 0; cf < 2; ++cf)
#pragma unroll
    for (int ks = 0; ks < 2; ++ks) {
      int row = wn*64 + cf*32 + l31;
      int lg  = row*64 + ks*32 + lr5*16;
      boff[cf][ks] = lg ^ (((row >> 3) & 1) << 5);
    }

  f32x16 acc[4][2] = {};

#define STAGE_A(kt) { const int bb_ = ((kt)&3)*16384; \
    GLDS16(Asrc0 + (size_t)(kt)*BK, AsC + bb_ + p0); \
    GLDS16(Asrc1 + (size_t)(kt)*BK, AsC + bb_ + p1); }
#define STAGE_B(kt) { const int bb_ = ((kt)&3)*16384; \
    GLDS16(Bsrc0 + (size_t)(kt)*BK, BsC + bb_ + p0); \
    GLDS16(Bsrc1 + (size_t)(kt)*BK, BsC + bb_ + p1); }
#define MFMA32(av, bv, c) __builtin_amdgcn_mfma_f32_32x32x16_bf16(av, bv, c, 0, 0, 0)

  // Prologue: stage tiles 0,1,2
  STAGE_A(0); STAGE_B(0);
  STAGE_A(1); STAGE_B(1);
  STAGE_A(2); STAGE_B(2);
  asm volatile("s_waitcnt vmcnt(8)" ::: "memory");   // tile 0 landed
  __builtin_amdgcn_sched_barrier(0);
  __builtin_amdgcn_s_barrier();
  __builtin_amdgcn_sched_barrier(0);

#pragma unroll 1
  for (int t = 0; t < NT; ++t) {
    const char* Ab = AsC + (t & 3) * 16384;
    const char* Bb = BsC + (t & 3) * 16384;

    // phase 1 (ks=0): 6 reads, stage A(t+3), 8 independent MFMA
    bf16x8 a0 = *(const bf16x8*)(Ab + aoff[0][0]);
    bf16x8 a1 = *(const bf16x8*)(Ab + aoff[1][0]);
    bf16x8 a2 = *(const bf16x8*)(Ab + aoff[2][0]);
    bf16x8 a3 = *(const bf16x8*)(Ab + aoff[3][0]);
    bf16x8 b0 = *(const bf16x8*)(Bb + boff[0][0]);
    bf16x8 b1 = *(const bf16x8*)(Bb + boff[1][0]);
    if (t + 3 < NT) STAGE_A(t + 3);
    __builtin_amdgcn_s_setprio(1);
    acc[0][0] = MFMA32(a0, b0, acc[0][0]);
    acc[0][1] = MFMA32(a0, b1, acc[0][1]);
    acc[1][0] = MFMA32(a1, b0, acc[1][0]);
    acc[1][1] = MFMA32(a1, b1, acc[1][1]);
    acc[2][0] = MFMA32(a2, b0, acc[2][0]);
    acc[2][1] = MFMA32(a2, b1, acc[2][1]);
    acc[3][0] = MFMA32(a3, b0, acc[3][0]);
    acc[3][1] = MFMA32(a3, b1, acc[3][1]);
    __builtin_amdgcn_s_setprio(0);

    // phase 2 (ks=1): 6 reads, stage B(t+3), 8 independent MFMA
    bf16x8 a4 = *(const bf16x8*)(Ab + aoff[0][1]);
    bf16x8 a5 = *(const bf16x8*)(Ab + aoff[1][1]);
    bf16x8 a6 = *(const bf16x8*)(Ab + aoff[2][1]);
    bf16x8 a7 = *(const bf16x8*)(Ab + aoff[3][1]);
    bf16x8 b2 = *(const bf16x8*)(Bb + boff[0][1]);
    bf16x8 b3 = *(const bf16x8*)(Bb + boff[1][1]);
    if (t + 3 < NT) STAGE_B(t + 3);
    __builtin_amdgcn_s_setprio(1);
    acc[0][0] = MFMA32(a4, b2, acc[0][0]);
    acc[0][1] = MFMA32(a4, b3, acc[0][1]);
    acc[1][0] = MFMA32(a5, b2, acc[1][0]);
    acc[1][1] = MFMA32(a5, b3, acc[1][1]);
    acc[2][0] = MFMA32(a6, b2, acc[2][0]);
    acc[2][1] = MFMA32(a6, b3, acc[2][1]);
    acc[3][0] = MFMA32(a7, b2, acc[3][0]);
    acc[3][1] = MFMA32(a7, b3, acc[3][1]);
    __builtin_amdgcn_s_setprio(0);

    // tile boundary: ONE counted vmcnt + ONE barrier
    if (t <= NT-4)      { asm volatile("s_waitcnt vmcnt(8)" ::: "memory"); }
    else if (t == NT-3) { asm volatile("s_waitcnt vmcnt(4)" ::: "memory"); }
    else                { asm volatile("s_waitcnt vmcnt(0)" ::: "memory"); }
    __builtin_amdgcn_sched_barrier(0);
    __builtin_amdgcn_s_barrier();
    __builtin_amdgcn_sched_barrier(0);
  }
#undef STAGE_A
#undef STAGE_B
#undef MFMA32

  // Epilogue: C-layout 32x32: col = l&31, row = (reg&3) + 8*(reg>>2) + 4*lr5
  const int orow = brow*256 + wm*128;
  const int ocol = bcol*256 + wn*64;
  if (Hb) {
#pragma unroll
    for (int cf = 0; cf < 2; ++cf) {
      const int c = ocol + cf*32 + l31;
      const float bias = bu[c];
#pragma unroll
      for (int rf = 0; rf < 4; ++rf) {
        const int br = orow + rf*32 + 4*lr5;
#pragma unroll
        for (int reg = 0; reg < 16; ++reg) {
          const int row = br + (reg & 3) + 8*(reg >> 2);
          Hb[(size_t)row*DIM + c] = f2bf(acc[rf][cf][reg] + bias);
        }
      }
    }
  } else {
#pragma unroll
    for (int cf = 0; cf < 2; ++cf) {
      const int c = ocol + cf*32 + l31;
      const float bias = bu[c];
#pragma unroll
      for (int rf = 0; rf < 4; ++rf) {
        const int br = orow + rf*32 + 4*lr5;
#pragma unroll
        for (int reg = 0; reg < 16; ++reg) {
          const int row = br + (reg & 3) + 8*(reg >> 2);
          Hf[(size_t)row*DIM + c] = acc[rf][cf][reg] + bias;
        }
      }
    }
  }
}

// ---------------- LN from bf16 H -> f32 out ----------------
__global__ __launch_bounds__(256) void ln_b(const u16* __restrict__ Hb,
                                            float* __restrict__ out,
                                            const float* __restrict__ gamma,
                                            const float* __restrict__ beta) {
  int row = blockIdx.x;
  const u16* h = Hb + (size_t)row*DIM;
  int tid = threadIdx.x;
  u16x8 hv = *reinterpret_cast<const u16x8*>(h + tid*8);
  float v[8];
#pragma unroll
  for (int j = 0; j < 8; ++j) v[j] = bf2f(hv[j]);
  float s = 0.f, s2 = 0.f;
#pragma unroll
  for (int j = 0; j < 8; ++j) { s += v[j]; s2 += v[j]*v[j]; }
#pragma unroll
  for (int o = 32; o >= 1; o >>= 1) { s += __shfl_xor(s, o); s2 += __shfl_xor(s2, o); }
  __shared__ float ss[4], ss2[4];
  int w = tid >> 6;
  if ((tid & 63) == 0) { ss[w] = s; ss2[w] = s2; }
  __syncthreads();
  s  = ss[0]+ss[1]+ss[2]+ss[3];
  s2 = ss2[0]+ss2[1]+ss2[2]+ss2[3];
  float mu  = s * (1.0f/DIM);
  float var = s2 * (1.0f/DIM) - mu*mu;
  float rs  = rsqrtf(var + 1e-5f);
  int c0 = tid*8;
  float o8[8];
#pragma unroll
  for (int j = 0; j < 8; ++j) o8[j] = (v[j]-mu)*rs*gamma[c0+j] + beta[c0+j];
  float4 oa = {o8[0],o8[1],o8[2],o8[3]}, ob = {o8[4],o8[5],o8[6],o8[7]};
  float* op = out + (size_t)row*DIM;
  reinterpret_cast<float4*>(op)[tid*2]   = oa;
  reinterpret_cast<float4*>(op)[tid*2+1] = ob;
}

// ---------------- LN in-place f32 (fallback) ----------------
__global__ __launch_bounds__(256) void ln_inplace(float* __restrict__ H,
                                                  const float* __restrict__ gamma,
                                                  const float* __restrict__ beta) {
  int row = blockIdx.x;
  float* h = H + (size_t)row*DIM;
  int tid = threadIdx.x;
  float4 a = reinterpret_cast<const float4*>(h)[tid*2];
  float4 b = reinterpret_cast<const float4*>(h)[tid*2+1];
  float v[8] = {a.x,a.y,a.z,a.w,b.x,b.y,b.z,b.w};
  float s = 0.f, s2 = 0.f;
#pragma unroll
  for (int j = 0; j < 8; ++j) { s += v[j]; s2 += v[j]*v[j]; }
#pragma unroll
  for (int o = 32; o >= 1; o >>= 1) { s += __shfl_xor(s, o); s2 += __shfl_xor(s2, o); }
  __shared__ float ss[4], ss2[4];
  int w = tid >> 6;
  if ((tid & 63) == 0) { ss[w] = s; ss2[w] = s2; }
  __syncthreads();
  s  = ss[0]+ss[1]+ss[2]+ss[3];
  s2 = ss2[0]+ss2[1]+ss2[2]+ss2[3];
  float mu  = s * (1.0f/DIM);
  float var = s2 * (1.0f/DIM) - mu*mu;
  float rs  = rsqrtf(var + 1e-5f);
  int c0 = tid*8;
  float o8[8];
#pragma unroll
  for (int j = 0; j < 8; ++j) o8[j] = (v[j]-mu)*rs*gamma[c0+j] + beta[c0+j];
  float4 oa = {o8[0],o8[1],o8[2],o8[3]}, ob = {o8[4],o8[5],o8[6],o8[7]};
  reinterpret_cast<float4*>(h)[tid*2]   = oa;
  reinterpret_cast<float4*>(h)[tid*2+1] = ob;
}

extern "C" void kernel_launch(void* const* d_in, const int* in_sizes, int n_in,
                              void* d_out, int out_size, void* d_ws, size_t ws_size,
                              hipStream_t stream) {
  const float* x     = (const float*)d_in[0];
  const float* ms    = (const float*)d_in[1];
  const float* Wg    = (const float*)d_in[2];
  const float* bg    = (const float*)d_in[3];
  const float* Wu    = (const float*)d_in[4];
  const float* bu    = (const float*)d_in[5];
  const float* gamma = (const float*)d_in[6];
  const float* beta  = (const float*)d_in[7];
  float* out = (float*)d_out;

  char* wsp = (char*)d_ws;
  const size_t offAcat  = 0;
  const size_t offWcatT = offAcat  + (size_t)MTOK*KC*2;      // 138,412,032
  const size_t offWgT   = offWcatT + (size_t)DIM*KC*2;       // +8,650,752
  const size_t offHb    = offWgT   + (size_t)MEM*DIM*2;      // +262,144
  const size_t needHb   = offHb + (size_t)MTOK*DIM*2;        // +134,217,728

  u16* Acat  = (u16*)(wsp + offAcat);
  u16* WcatT = (u16*)(wsp + offWcatT);
  u16* WgT   = (u16*)(wsp + offWgT);
  float* M2p = (float*)wsp;  // aliases Acat (consumed before conv_x)
  u16* Hb    = (ws_size >= needHb) ? (u16*)(wsp + offHb) : nullptr;

  prep_m2a<<<dim3(8,16,8), 256, 0, stream>>>(ms, Wu, M2p);
  prep_m2b<<<512, 256, 0, stream>>>(M2p, WcatT);
  prep_wu1<<<1024, 256, 0, stream>>>(Wu, WcatT);
  prep_wg<<<32, 256, 0, stream>>>(Wg, WgT);
  conv_x<<<32768, 256, 0, stream>>>(x, Acat);
  gates_gemm<<<256, 256, 0, stream>>>(Acat, WgT, bg, Acat);
  gemm_main8<<<1024, 512, 0, stream>>>(Acat, WcatT, bu, out, Hb);
  if (Hb) ln_b<<<32768, 256, 0, stream>>>(Hb, out, gamma, beta);
  else    ln_inplace<<<32768, 256, 0, stream>>>(out, gamma, beta);
}